// Round 2
// baseline (654.631 us; speedup 1.0000x reference)
//
#include <hip/hip_runtime.h>
#include <hip/hip_bf16.h>
#include <cstdint>
#include <cstddef>

// ---------------------------------------------------------------------------
// CausalSelfAttention fused block, MI355X/gfx950.  Round 2: split-precision
// (hi/lo bf16) on the q/k logit chain to clear the 0.13 absmax threshold.
// B=2 T=2048 D=2048 NH=16 NKV=4 HD=128 ROPE=64.
// ---------------------------------------------------------------------------

typedef __bf16 bf16_t;
typedef bf16_t bf16x8 __attribute__((ext_vector_type(8)));
typedef float f32x4 __attribute__((ext_vector_type(4)));

#define MFMA16(a, b, c) __builtin_amdgcn_mfma_f32_16x16x32_bf16((a), (b), (c), 0, 0, 0)

__device__ __forceinline__ bf16_t to_bf16(float f) {
  __hip_bfloat16 h = __float2bfloat16(f);
  return *reinterpret_cast<bf16_t*>(&h);
}

__device__ __forceinline__ void gload16(const bf16_t* g, bf16_t* l) {
  auto lds_ptr = reinterpret_cast<__attribute__((address_space(3))) unsigned int*>(
      reinterpret_cast<uintptr_t>(l));
  auto g_ptr = reinterpret_cast<const __attribute__((address_space(1))) unsigned int*>(
      reinterpret_cast<uintptr_t>(g));
  __builtin_amdgcn_global_load_lds(g_ptr, lds_ptr, 16, 0, 0);
}

// ---------------------------------------------------------------------------
// fp32 -> bf16 cast, vectorized
// ---------------------------------------------------------------------------
__global__ void k_cast_bf16(const float* __restrict__ in, bf16_t* __restrict__ o, long n) {
  long i = ((long)blockIdx.x * blockDim.x + threadIdx.x) * 4;
  const long step = (long)gridDim.x * blockDim.x * 4;
  for (; i < n; i += step) {
    const float4 v = *reinterpret_cast<const float4*>(in + i);
    bf16_t r[4] = {to_bf16(v.x), to_bf16(v.y), to_bf16(v.z), to_bf16(v.w)};
    *reinterpret_cast<uint64_t*>(o + i) = *reinterpret_cast<const uint64_t*>(r);
  }
}

// ---------------------------------------------------------------------------
// x split: in [4096][2048] fp32 -> x2 [4096][4096] bf16, cols 0-2047 = hi,
// cols 2048-4095 = lo (residual).
// ---------------------------------------------------------------------------
__global__ void k_split_x(const float* __restrict__ in, bf16_t* __restrict__ x2) {
  long i = ((long)blockIdx.x * blockDim.x + threadIdx.x) * 4;
  const long step = (long)gridDim.x * blockDim.x * 4;
  for (; i < (long)4096 * 2048; i += step) {
    const float4 v = *reinterpret_cast<const float4*>(in + i);
    const long row = i >> 11, col = i & 2047;
    bf16_t h[4], l[4];
    const float vv[4] = {v.x, v.y, v.z, v.w};
#pragma unroll
    for (int j = 0; j < 4; ++j) {
      h[j] = to_bf16(vv[j]);
      l[j] = to_bf16(vv[j] - (float)h[j]);
    }
    *reinterpret_cast<uint64_t*>(x2 + row * 4096 + col) = *reinterpret_cast<const uint64_t*>(h);
    *reinterpret_cast<uint64_t*>(x2 + row * 4096 + 2048 + col) = *reinterpret_cast<const uint64_t*>(l);
  }
}

// ---------------------------------------------------------------------------
// W split: W [R][2048] fp32 -> w2 [R][4096] = [hi|hi] (duplicated), wl [R][2048] = lo
// ---------------------------------------------------------------------------
__global__ void k_split_w(const float* __restrict__ W, bf16_t* __restrict__ w2,
                          bf16_t* __restrict__ wl, long n) {
  long i = ((long)blockIdx.x * blockDim.x + threadIdx.x) * 4;
  const long step = (long)gridDim.x * blockDim.x * 4;
  for (; i < n; i += step) {
    const float4 v = *reinterpret_cast<const float4*>(W + i);
    const long row = i >> 11, col = i & 2047;
    bf16_t h[4], l[4];
    const float vv[4] = {v.x, v.y, v.z, v.w};
#pragma unroll
    for (int j = 0; j < 4; ++j) {
      h[j] = to_bf16(vv[j]);
      l[j] = to_bf16(vv[j] - (float)h[j]);
    }
    const uint64_t h64 = *reinterpret_cast<const uint64_t*>(h);
    *reinterpret_cast<uint64_t*>(w2 + row * 4096 + col) = h64;
    *reinterpret_cast<uint64_t*>(w2 + row * 4096 + 2048 + col) = h64;
    *reinterpret_cast<uint64_t*>(wl + row * 2048 + col) = *reinterpret_cast<const uint64_t*>(l);
  }
}

// ---------------------------------------------------------------------------
// RoPE cos/sin table: [T=2048][32]
// ---------------------------------------------------------------------------
__global__ void k_rope_tab(float* __restrict__ ctab, float* __restrict__ stab) {
  const int idx = blockIdx.x * blockDim.x + threadIdx.x;
  if (idx >= 2048 * 32) return;
  const int t = idx >> 5, i = idx & 31;
  const float freq = exp2f(-(float)i * 0.2076205059304601f);  // 10000^(-i/64)
  const float f = (float)t * freq;
  ctab[idx] = cosf(f);
  stab[idx] = sinf(f);
}

// ---------------------------------------------------------------------------
// NT GEMM: C[m,n] (+)= sum_k A[m,k]*B[n,k].  A row stride lda, B row stride
// ldb (elements).  128x128 tile, BK=32, 4 waves, double-buffered LDS via
// global_load_lds(16B), XOR slot swizzle.
// ---------------------------------------------------------------------------
template <bool ACC>
__global__ __launch_bounds__(256, 2) void k_gemm_bt(
    const bf16_t* __restrict__ A, const bf16_t* __restrict__ Bm,
    float* __restrict__ C, int M, int N, int K, int lda, int ldb)
{
  __shared__ __align__(16) bf16_t lsA[2][128 * 32];
  __shared__ __align__(16) bf16_t lsB[2][128 * 32];
  const int tid = threadIdx.x;
  const int w = tid >> 6, l = tid & 63;
  const int lrow = l & 15, lk = l >> 4;
  const int m0 = blockIdx.y * 128, n0 = blockIdx.x * 128;
  const int wm = w >> 1, wn = w & 1;

  const int r0 = tid >> 2;
  const int sl = tid & 3;
  const int ls0 = sl ^ ((r0 >> 1) & 3);
  const int r1 = r0 + 64;
  const int ls1 = sl ^ ((r1 >> 1) & 3);
  const bf16_t* gA0 = A + (size_t)(m0 + r0) * lda + ls0 * 8;
  const bf16_t* gA1 = A + (size_t)(m0 + r1) * lda + ls1 * 8;
  const bf16_t* gB0 = Bm + (size_t)(n0 + r0) * ldb + ls0 * 8;
  const bf16_t* gB1 = Bm + (size_t)(n0 + r1) * ldb + ls1 * 8;
  const int lofs = tid * 8;

  f32x4 acc[4][4] = {};
  const int nkt = K >> 5;

  gload16(gA0, &lsA[0][lofs]);
  gload16(gA1, &lsA[0][lofs + 2048]);
  gload16(gB0, &lsB[0][lofs]);
  gload16(gB1, &lsB[0][lofs + 2048]);
  __syncthreads();

  for (int kt = 0; kt < nkt; ++kt) {
    const int buf = kt & 1;
    if (kt + 1 < nkt) {
      const int ko = (kt + 1) << 5;
      gload16(gA0 + ko, &lsA[buf ^ 1][lofs]);
      gload16(gA1 + ko, &lsA[buf ^ 1][lofs + 2048]);
      gload16(gB0 + ko, &lsB[buf ^ 1][lofs]);
      gload16(gB1 + ko, &lsB[buf ^ 1][lofs + 2048]);
    }
    bf16x8 af[4], bfv[4];
#pragma unroll
    for (int mi = 0; mi < 4; ++mi) {
      const int r = wm * 64 + mi * 16 + lrow;
      const int ps = lk ^ ((r >> 1) & 3);
      af[mi] = *reinterpret_cast<const bf16x8*>(&lsA[buf][r * 32 + ps * 8]);
    }
#pragma unroll
    for (int ni = 0; ni < 4; ++ni) {
      const int r = wn * 64 + ni * 16 + lrow;
      const int ps = lk ^ ((r >> 1) & 3);
      bfv[ni] = *reinterpret_cast<const bf16x8*>(&lsB[buf][r * 32 + ps * 8]);
    }
#pragma unroll
    for (int mi = 0; mi < 4; ++mi)
#pragma unroll
      for (int ni = 0; ni < 4; ++ni)
        acc[mi][ni] = MFMA16(af[mi], bfv[ni], acc[mi][ni]);
    __syncthreads();
  }

  // C/D layout: col = lane&15, row = (lane>>4)*4 + reg
#pragma unroll
  for (int mi = 0; mi < 4; ++mi) {
    const int row = m0 + wm * 64 + mi * 16 + lk * 4;
#pragma unroll
    for (int ni = 0; ni < 4; ++ni) {
      const int col = n0 + wn * 64 + ni * 16 + lrow;
#pragma unroll
      for (int rg = 0; rg < 4; ++rg) {
        const size_t idx = (size_t)(row + rg) * N + col;
        if constexpr (ACC) C[idx] += acc[mi][ni][rg];
        else               C[idx]  = acc[mi][ni][rg];
      }
    }
  }
}

// ---------------------------------------------------------------------------
// QKV epilogue: RMS-norm(q,k) + partial RoPE + q_gain (fp32), then hi/lo bf16
// split for q,k ; v += ve_embed (plain bf16).
// qn2 [B][NH][T][256] (hi|lo), kn2 [B][NKV][T][256], vn [B][NKV][T][128].
// ---------------------------------------------------------------------------
__global__ __launch_bounds__(256) void k_qkv_epi(
    const float* __restrict__ qraw, const float* __restrict__ kvraw,
    const float* __restrict__ ve, const float* __restrict__ qgain,
    const float* __restrict__ ctab, const float* __restrict__ stab,
    bf16_t* __restrict__ qn2, bf16_t* __restrict__ kn2, bf16_t* __restrict__ vn)
{
  const int blk = blockIdx.x;           // b*2048 + t
  const int b = blk >> 11, t = blk & 2047;
  const int w = threadIdx.x >> 6, l = threadIdx.x & 63;
  const int i32 = l & 31;
  const float c = ctab[t * 32 + i32], s = stab[t * 32 + i32];
  const float EPS = 1.1920929e-07f;

  auto store_hl = [&](bf16_t* orow, int d, float v) {
    const bf16_t h = to_bf16(v);
    orow[d] = h;
    orow[128 + d] = to_bf16(v - (float)h);
  };

  // Q: wave w handles heads w, w+4, w+8, w+12
#pragma unroll
  for (int it = 0; it < 4; ++it) {
    const int h = w + it * 4;
    const float* row = qraw + (size_t)blk * 2048 + h * 128;
    float x0 = row[l], x1 = row[l + 64];
    float ss = x0 * x0 + x1 * x1;
#pragma unroll
    for (int off = 32; off; off >>= 1) ss += __shfl_xor(ss, off);
    const float rn = rsqrtf(ss * (1.0f / 128.0f) + EPS);
    x0 *= rn; x1 *= rn;
    const float p = __shfl_xor(x0, 32);
    float xr = (l < 32) ? (x0 * c - p * s) : (p * s + x0 * c);
    const float g = qgain[h];
    xr *= g; x1 *= g;
    bf16_t* orow = qn2 + (((size_t)(b * 16 + h)) * 2048 + t) * 256;
    store_hl(orow, l, xr);
    store_hl(orow, l + 64, x1);
  }
  // K: wave w -> kv head w
  {
    const float* row = kvraw + (size_t)blk * 1024 + w * 128;
    float x0 = row[l], x1 = row[l + 64];
    float ss = x0 * x0 + x1 * x1;
#pragma unroll
    for (int off = 32; off; off >>= 1) ss += __shfl_xor(ss, off);
    const float rn = rsqrtf(ss * (1.0f / 128.0f) + EPS);
    x0 *= rn; x1 *= rn;
    const float p = __shfl_xor(x0, 32);
    float xr = (l < 32) ? (x0 * c - p * s) : (p * s + x0 * c);
    bf16_t* orow = kn2 + (((size_t)(b * 4 + w)) * 2048 + t) * 256;
    store_hl(orow, l, xr);
    store_hl(orow, l + 64, x1);
  }
  // V: wave w -> kv head w ; v = vraw + ve
  {
    const float* row = kvraw + (size_t)blk * 1024 + 512 + w * 128;
    const float* verow = ve + (size_t)blk * 512 + w * 128;
    bf16_t* orow = vn + (((size_t)(b * 4 + w)) * 2048 + t) * 128;
    orow[l] = to_bf16(row[l] + verow[l]);
    orow[l + 64] = to_bf16(row[l + 64] + verow[l + 64]);
  }
}

// ---------------------------------------------------------------------------
// Causal GQA flash attention, hi/lo q,k (3-term QK^T).
// Block = (qt, b*16+h), 4 waves x 32 q-rows, KVBLK=64.
// lsK[0]=K_hi [64][136], lsK[1]=K_lo [64][136]; after S-step + sync the same
// storage holds per-wave P tiles [32][72].  lsV = V^T [128][72].
// ---------------------------------------------------------------------------
__global__ __launch_bounds__(256, 2) void k_attn(
    const bf16_t* __restrict__ qn2, const bf16_t* __restrict__ kn2,
    const bf16_t* __restrict__ vn, bf16_t* __restrict__ y)
{
  __shared__ __align__(16) bf16_t lsK[2][64 * 136];   // 34816 B (also P scratch)
  __shared__ __align__(16) bf16_t lsV[128 * 72];      // 18432 B
  const int qt = blockIdx.x;            // 0..15
  const int bh = blockIdx.y;            // 0..31
  const int b = bh >> 4, h = bh & 15, kvh = h >> 2;
  const int tid = threadIdx.x, w = tid >> 6, l = tid & 63;
  const int lrow = l & 15, lk = l >> 4;
  const int q0 = qt * 128;
  const int qbase = q0 + w * 32;
  constexpr float SCALE = 0.088388347648318447f;  // 1/sqrt(128)
  constexpr float NEG = -1e30f;
  bf16_t* lsP = &lsK[0][0] + w * (32 * 72);       // per-wave P tile

  // Q fragments (A-frag: row = lane&15, k = (lane>>4)*8+j), hi and lo
  const bf16_t* qp = qn2 + ((size_t)(b * 16 + h) * 2048) * 256;
  bf16x8 aQh[2][4], aQl[2][4];
#pragma unroll
  for (int rf = 0; rf < 2; ++rf)
#pragma unroll
    for (int kf = 0; kf < 4; ++kf) {
      const size_t base = (size_t)(qbase + rf * 16 + lrow) * 256 + kf * 32 + lk * 8;
      aQh[rf][kf] = *reinterpret_cast<const bf16x8*>(qp + base);
      aQl[rf][kf] = *reinterpret_cast<const bf16x8*>(qp + base + 128);
    }

  const bf16_t* kp = kn2 + ((size_t)(b * 4 + kvh) * 2048) * 256;
  const bf16_t* vp = vn + ((size_t)(b * 4 + kvh) * 2048) * 128;

  f32x4 o[2][8] = {};
  float mstate[2][4], lstate[2][4];
#pragma unroll
  for (int rf = 0; rf < 2; ++rf)
#pragma unroll
    for (int rg = 0; rg < 4; ++rg) { mstate[rf][rg] = NEG; lstate[rf][rg] = 0.f; }

  const int ntiles = qt * 2 + 2;
  for (int tt = 0; tt < ntiles; ++tt) {
    const int t0 = tt * 64;
    __syncthreads();  // prior tile's P/V reads done before restage
    // stage K hi+lo: 64 rows x 256 cols (hi 0-127 -> lsK[0], lo 128-255 -> lsK[1])
#pragma unroll
    for (int it = 0; it < 8; ++it) {
      const int cch = tid + it * 256;
      const int r = cch >> 5, c5 = cch & 31;
      const bf16x8 v8 = *reinterpret_cast<const bf16x8*>(kp + (size_t)(t0 + r) * 256 + c5 * 8);
      if (c5 < 16) *reinterpret_cast<bf16x8*>(&lsK[0][r * 136 + c5 * 8]) = v8;
      else         *reinterpret_cast<bf16x8*>(&lsK[1][r * 136 + (c5 - 16) * 8]) = v8;
    }
    // stage V^T [128 d][72 kv]
#pragma unroll
    for (int it = 0; it < 4; ++it) {
      const int cch = tid + it * 256;
      const int kv = cch >> 4, dg = cch & 15;
      const bf16x8 v8 = *reinterpret_cast<const bf16x8*>(vp + (size_t)(t0 + kv) * 128 + dg * 8);
#pragma unroll
      for (int j = 0; j < 8; ++j) lsV[(dg * 8 + j) * 72 + kv] = v8[j];
    }
    __syncthreads();

    // S = Qh*Kh + Ql*Kh + Qh*Kl
    f32x4 sacc[2][4] = {};
#pragma unroll
    for (int cf = 0; cf < 4; ++cf)
#pragma unroll
      for (int kf = 0; kf < 4; ++kf) {
        const int ofs = (cf * 16 + lrow) * 136 + kf * 32 + lk * 8;
        const bf16x8 bKh = *reinterpret_cast<const bf16x8*>(&lsK[0][ofs]);
        const bf16x8 bKl = *reinterpret_cast<const bf16x8*>(&lsK[1][ofs]);
        sacc[0][cf] = MFMA16(aQh[0][kf], bKh, sacc[0][cf]);
        sacc[1][cf] = MFMA16(aQh[1][kf], bKh, sacc[1][cf]);
        sacc[0][cf] = MFMA16(aQl[0][kf], bKh, sacc[0][cf]);
        sacc[1][cf] = MFMA16(aQl[1][kf], bKh, sacc[1][cf]);
        sacc[0][cf] = MFMA16(aQh[0][kf], bKl, sacc[0][cf]);
        sacc[1][cf] = MFMA16(aQh[1][kf], bKl, sacc[1][cf]);
      }
    __syncthreads();  // all waves done reading K before P overwrites it

    // online softmax (rows: q = qbase + rf*16 + lk*4 + rg ; cols kv = cf*16+lrow)
    const bool domask = (tt >= 2 * qt);
#pragma unroll
    for (int rf = 0; rf < 2; ++rf)
#pragma unroll
      for (int rg = 0; rg < 4; ++rg) {
        const int qi = qbase + rf * 16 + lk * 4 + rg;
        float mx = NEG;
#pragma unroll
        for (int cf = 0; cf < 4; ++cf) {
          float sv = sacc[rf][cf][rg] * SCALE;
          if (domask && (t0 + cf * 16 + lrow > qi)) sv = NEG;
          sacc[rf][cf][rg] = sv;
          mx = fmaxf(mx, sv);
        }
        mx = fmaxf(mx, __shfl_xor(mx, 1));
        mx = fmaxf(mx, __shfl_xor(mx, 2));
        mx = fmaxf(mx, __shfl_xor(mx, 4));
        mx = fmaxf(mx, __shfl_xor(mx, 8));
        const float mold = mstate[rf][rg];
        const float mnew = fmaxf(mold, mx);
        mstate[rf][rg] = mnew;
        const float alpha = __expf(mold - mnew);
        float rsum = 0.f;
#pragma unroll
        for (int cf = 0; cf < 4; ++cf) {
          const float p = __expf(sacc[rf][cf][rg] - mnew);
          sacc[rf][cf][rg] = p;
          rsum += p;
        }
        rsum += __shfl_xor(rsum, 1);
        rsum += __shfl_xor(rsum, 2);
        rsum += __shfl_xor(rsum, 4);
        rsum += __shfl_xor(rsum, 8);
        lstate[rf][rg] = lstate[rf][rg] * alpha + rsum;
#pragma unroll
        for (int df = 0; df < 8; ++df) o[rf][df][rg] *= alpha;
      }

    // P -> per-wave LDS (A-frag layout), then PV
#pragma unroll
    for (int rf = 0; rf < 2; ++rf)
#pragma unroll
      for (int cf = 0; cf < 4; ++cf)
#pragma unroll
        for (int rg = 0; rg < 4; ++rg)
          lsP[(rf * 16 + lk * 4 + rg) * 72 + cf * 16 + lrow] =
              to_bf16(sacc[rf][cf][rg]);
#pragma unroll
    for (int k2 = 0; k2 < 2; ++k2) {
      bf16x8 aP0 = *reinterpret_cast<const bf16x8*>(&lsP[lrow * 72 + k2 * 32 + lk * 8]);
      bf16x8 aP1 = *reinterpret_cast<const bf16x8*>(&lsP[(16 + lrow) * 72 + k2 * 32 + lk * 8]);
#pragma unroll
      for (int df = 0; df < 8; ++df) {
        const bf16x8 bV = *reinterpret_cast<const bf16x8*>(
            &lsV[(df * 16 + lrow) * 72 + k2 * 32 + lk * 8]);
        o[0][df] = MFMA16(aP0, bV, o[0][df]);
        o[1][df] = MFMA16(aP1, bV, o[1][df]);
      }
    }
  }

  // normalize + write y [b][t][h*128+d]
#pragma unroll
  for (int rf = 0; rf < 2; ++rf)
#pragma unroll
    for (int rg = 0; rg < 4; ++rg) {
      const float inv = 1.0f / lstate[rf][rg];
      const int qi = qbase + rf * 16 + lk * 4 + rg;
      const size_t rowoff = ((size_t)(b * 2048 + qi)) * 2048 + h * 128;
#pragma unroll
      for (int df = 0; df < 8; ++df)
        y[rowoff + df * 16 + lrow] = to_bf16(o[rf][df][rg] * inv);
    }
}

// ---------------------------------------------------------------------------
extern "C" void kernel_launch(void* const* d_in, const int* in_sizes, int n_in,
                              void* d_out, int out_size, void* d_ws, size_t ws_size,
                              hipStream_t stream) {
  const float* x  = (const float*)d_in[0];
  const float* ve = (const float*)d_in[1];
  const float* Wq = (const float*)d_in[2];
  const float* Wk = (const float*)d_in[3];
  const float* Wv = (const float*)d_in[4];
  const float* Wp = (const float*)d_in[5];
  const float* qg = (const float*)d_in[6];
  float* out = (float*)d_out;

  char* ws = (char*)d_ws;
  size_t off = 0;
  auto alloc = [&](size_t bytes) -> char* {
    char* p = ws + off;
    off += (bytes + 255) & ~(size_t)255;
    return p;
  };

  bf16_t* x2    = (bf16_t*)alloc((size_t)4096 * 4096 * 2);  // [xh|xl]; later qn2
  bf16_t* wq2   = (bf16_t*)alloc((size_t)2048 * 4096 * 2);  // [Wqh|Wqh]
  bf16_t* wql   = (bf16_t*)alloc((size_t)2048 * 2048 * 2);
  bf16_t* wkv2  = (bf16_t*)alloc((size_t)1024 * 4096 * 2);  // rows: Wk then Wv
  bf16_t* wkvl  = (bf16_t*)alloc((size_t)1024 * 2048 * 2);
  bf16_t* wpb   = (bf16_t*)alloc((size_t)2048 * 2048 * 2);
  float*  qraw  = (float*)alloc((size_t)4096 * 2048 * 4);
  float*  kvraw = (float*)alloc((size_t)4096 * 1024 * 4);   // later yb
  bf16_t* kn2   = (bf16_t*)alloc((size_t)2 * 4 * 2048 * 256 * 2);
  bf16_t* vn    = (bf16_t*)alloc((size_t)2 * 4 * 2048 * 128 * 2);
  float*  ctab  = (float*)alloc((size_t)2048 * 32 * 4);
  float*  stab  = (float*)alloc((size_t)2048 * 32 * 4);
  bf16_t* qn2   = x2;              // x2 dead after GEMMs
  bf16_t* yb    = (bf16_t*)kvraw;  // kvraw dead after epilogue
  (void)ws_size; (void)in_sizes; (void)n_in; (void)out_size;

  k_split_x<<<2048, 256, 0, stream>>>(x, x2);
  k_split_w<<<1024, 256, 0, stream>>>(Wq, wq2, wql, (long)2048 * 2048);
  k_split_w<<<512,  256, 0, stream>>>(Wk, wkv2, wkvl, (long)512 * 2048);
  k_split_w<<<512,  256, 0, stream>>>(Wv, wkv2 + (size_t)512 * 4096,
                                      wkvl + (size_t)512 * 2048, (long)512 * 2048);
  k_cast_bf16<<<1024, 256, 0, stream>>>(Wp, wpb, (long)2048 * 2048);
  k_rope_tab<<<256, 256, 0, stream>>>(ctab, stab);

  // qraw = [xh|xl]·[Wh|Wh]^T + xh·Wl^T
  k_gemm_bt<false><<<dim3(16, 32), 256, 0, stream>>>(x2, wq2, qraw, 4096, 2048, 4096, 4096, 4096);
  k_gemm_bt<true ><<<dim3(16, 32), 256, 0, stream>>>(x2, wql, qraw, 4096, 2048, 2048, 4096, 2048);
  k_gemm_bt<false><<<dim3(8, 32),  256, 0, stream>>>(x2, wkv2, kvraw, 4096, 1024, 4096, 4096, 4096);
  k_gemm_bt<true ><<<dim3(8, 32),  256, 0, stream>>>(x2, wkvl, kvraw, 4096, 1024, 2048, 4096, 2048);

  k_qkv_epi<<<4096, 256, 0, stream>>>(qraw, kvraw, ve, qg, ctab, stab, qn2, kn2, vn);

  k_attn<<<dim3(16, 32), 256, 0, stream>>>(qn2, kn2, vn, yb);

  k_gemm_bt<false><<<dim3(16, 32), 256, 0, stream>>>(yb, wpb, out, 4096, 2048, 2048, 2048, 2048);
}

// Round 3
// 506.894 us; speedup vs baseline: 1.2915x; 1.2915x over previous
//
#include <hip/hip_runtime.h>
#include <hip/hip_bf16.h>
#include <cstdint>
#include <cstddef>

// ---------------------------------------------------------------------------
// CausalSelfAttention fused block, MI355X/gfx950.  Round 3:
//  - attn: QBLK=64 (1024 blocks, longest-first), V^T XOR-swizzled staging
//  - QKV projections folded into single K=6144 GEMMs (no ACC pass)
// B=2 T=2048 D=2048 NH=16 NKV=4 HD=128 ROPE=64.
// ---------------------------------------------------------------------------

typedef __bf16 bf16_t;
typedef bf16_t bf16x8 __attribute__((ext_vector_type(8)));
typedef float f32x4 __attribute__((ext_vector_type(4)));

#define MFMA16(a, b, c) __builtin_amdgcn_mfma_f32_16x16x32_bf16((a), (b), (c), 0, 0, 0)

__device__ __forceinline__ bf16_t to_bf16(float f) {
  __hip_bfloat16 h = __float2bfloat16(f);
  return *reinterpret_cast<bf16_t*>(&h);
}

__device__ __forceinline__ void gload16(const bf16_t* g, bf16_t* l) {
  auto lds_ptr = reinterpret_cast<__attribute__((address_space(3))) unsigned int*>(
      reinterpret_cast<uintptr_t>(l));
  auto g_ptr = reinterpret_cast<const __attribute__((address_space(1))) unsigned int*>(
      reinterpret_cast<uintptr_t>(g));
  __builtin_amdgcn_global_load_lds(g_ptr, lds_ptr, 16, 0, 0);
}

// ---------------------------------------------------------------------------
// fp32 -> bf16 cast, vectorized
// ---------------------------------------------------------------------------
__global__ void k_cast_bf16(const float* __restrict__ in, bf16_t* __restrict__ o, long n) {
  long i = ((long)blockIdx.x * blockDim.x + threadIdx.x) * 4;
  const long step = (long)gridDim.x * blockDim.x * 4;
  for (; i < n; i += step) {
    const float4 v = *reinterpret_cast<const float4*>(in + i);
    bf16_t r[4] = {to_bf16(v.x), to_bf16(v.y), to_bf16(v.z), to_bf16(v.w)};
    *reinterpret_cast<uint64_t*>(o + i) = *reinterpret_cast<const uint64_t*>(r);
  }
}

// ---------------------------------------------------------------------------
// x split: in [4096][2048] fp32 -> x3 [4096][6144] bf16 = [xh | xl | xh]
// ---------------------------------------------------------------------------
__global__ void k_split_x(const float* __restrict__ in, bf16_t* __restrict__ x3) {
  long i = ((long)blockIdx.x * blockDim.x + threadIdx.x) * 4;
  const long step = (long)gridDim.x * blockDim.x * 4;
  for (; i < (long)4096 * 2048; i += step) {
    const float4 v = *reinterpret_cast<const float4*>(in + i);
    const long row = i >> 11, col = i & 2047;
    bf16_t h[4], l[4];
    const float vv[4] = {v.x, v.y, v.z, v.w};
#pragma unroll
    for (int j = 0; j < 4; ++j) {
      h[j] = to_bf16(vv[j]);
      l[j] = to_bf16(vv[j] - (float)h[j]);
    }
    const uint64_t h64 = *reinterpret_cast<const uint64_t*>(h);
    bf16_t* rp = x3 + row * 6144;
    *reinterpret_cast<uint64_t*>(rp + col) = h64;
    *reinterpret_cast<uint64_t*>(rp + 2048 + col) = *reinterpret_cast<const uint64_t*>(l);
    *reinterpret_cast<uint64_t*>(rp + 4096 + col) = h64;
  }
}

// ---------------------------------------------------------------------------
// W split: W [R][2048] fp32 -> w3 [R][6144] = [Wh | Wh | Wl]
// ---------------------------------------------------------------------------
__global__ void k_split_w(const float* __restrict__ W, bf16_t* __restrict__ w3, long n) {
  long i = ((long)blockIdx.x * blockDim.x + threadIdx.x) * 4;
  const long step = (long)gridDim.x * blockDim.x * 4;
  for (; i < n; i += step) {
    const float4 v = *reinterpret_cast<const float4*>(W + i);
    const long row = i >> 11, col = i & 2047;
    bf16_t h[4], l[4];
    const float vv[4] = {v.x, v.y, v.z, v.w};
#pragma unroll
    for (int j = 0; j < 4; ++j) {
      h[j] = to_bf16(vv[j]);
      l[j] = to_bf16(vv[j] - (float)h[j]);
    }
    const uint64_t h64 = *reinterpret_cast<const uint64_t*>(h);
    bf16_t* rp = w3 + row * 6144;
    *reinterpret_cast<uint64_t*>(rp + col) = h64;
    *reinterpret_cast<uint64_t*>(rp + 2048 + col) = h64;
    *reinterpret_cast<uint64_t*>(rp + 4096 + col) = *reinterpret_cast<const uint64_t*>(l);
  }
}

// ---------------------------------------------------------------------------
// RoPE cos/sin table: [T=2048][32]
// ---------------------------------------------------------------------------
__global__ void k_rope_tab(float* __restrict__ ctab, float* __restrict__ stab) {
  const int idx = blockIdx.x * blockDim.x + threadIdx.x;
  if (idx >= 2048 * 32) return;
  const int t = idx >> 5, i = idx & 31;
  const float freq = exp2f(-(float)i * 0.2076205059304601f);  // 10000^(-i/64)
  const float f = (float)t * freq;
  ctab[idx] = cosf(f);
  stab[idx] = sinf(f);
}

// ---------------------------------------------------------------------------
// NT GEMM: C[m,n] = sum_k A[m,k]*B[n,k].  Row strides lda/ldb (elements).
// 128x128 tile, BK=32, 4 waves, double-buffered LDS via global_load_lds(16B),
// XOR slot swizzle.
// ---------------------------------------------------------------------------
__global__ __launch_bounds__(256, 2) void k_gemm_bt(
    const bf16_t* __restrict__ A, const bf16_t* __restrict__ Bm,
    float* __restrict__ C, int M, int N, int K, int lda, int ldb)
{
  __shared__ __align__(16) bf16_t lsA[2][128 * 32];
  __shared__ __align__(16) bf16_t lsB[2][128 * 32];
  const int tid = threadIdx.x;
  const int w = tid >> 6, l = tid & 63;
  const int lrow = l & 15, lk = l >> 4;
  const int m0 = blockIdx.y * 128, n0 = blockIdx.x * 128;
  const int wm = w >> 1, wn = w & 1;

  const int r0 = tid >> 2;
  const int sl = tid & 3;
  const int ls0 = sl ^ ((r0 >> 1) & 3);
  const int r1 = r0 + 64;
  const int ls1 = sl ^ ((r1 >> 1) & 3);
  const bf16_t* gA0 = A + (size_t)(m0 + r0) * lda + ls0 * 8;
  const bf16_t* gA1 = A + (size_t)(m0 + r1) * lda + ls1 * 8;
  const bf16_t* gB0 = Bm + (size_t)(n0 + r0) * ldb + ls0 * 8;
  const bf16_t* gB1 = Bm + (size_t)(n0 + r1) * ldb + ls1 * 8;
  const int lofs = tid * 8;

  f32x4 acc[4][4] = {};
  const int nkt = K >> 5;

  gload16(gA0, &lsA[0][lofs]);
  gload16(gA1, &lsA[0][lofs + 2048]);
  gload16(gB0, &lsB[0][lofs]);
  gload16(gB1, &lsB[0][lofs + 2048]);
  __syncthreads();

  for (int kt = 0; kt < nkt; ++kt) {
    const int buf = kt & 1;
    if (kt + 1 < nkt) {
      const int ko = (kt + 1) << 5;
      gload16(gA0 + ko, &lsA[buf ^ 1][lofs]);
      gload16(gA1 + ko, &lsA[buf ^ 1][lofs + 2048]);
      gload16(gB0 + ko, &lsB[buf ^ 1][lofs]);
      gload16(gB1 + ko, &lsB[buf ^ 1][lofs + 2048]);
    }
    bf16x8 af[4], bfv[4];
#pragma unroll
    for (int mi = 0; mi < 4; ++mi) {
      const int r = wm * 64 + mi * 16 + lrow;
      const int ps = lk ^ ((r >> 1) & 3);
      af[mi] = *reinterpret_cast<const bf16x8*>(&lsA[buf][r * 32 + ps * 8]);
    }
#pragma unroll
    for (int ni = 0; ni < 4; ++ni) {
      const int r = wn * 64 + ni * 16 + lrow;
      const int ps = lk ^ ((r >> 1) & 3);
      bfv[ni] = *reinterpret_cast<const bf16x8*>(&lsB[buf][r * 32 + ps * 8]);
    }
#pragma unroll
    for (int mi = 0; mi < 4; ++mi)
#pragma unroll
      for (int ni = 0; ni < 4; ++ni)
        acc[mi][ni] = MFMA16(af[mi], bfv[ni], acc[mi][ni]);
    __syncthreads();
  }

  // C/D layout: col = lane&15, row = (lane>>4)*4 + reg
#pragma unroll
  for (int mi = 0; mi < 4; ++mi) {
    const int row = m0 + wm * 64 + mi * 16 + lk * 4;
#pragma unroll
    for (int ni = 0; ni < 4; ++ni) {
      const int col = n0 + wn * 64 + ni * 16 + lrow;
#pragma unroll
      for (int rg = 0; rg < 4; ++rg)
        C[(size_t)(row + rg) * N + col] = acc[mi][ni][rg];
    }
  }
}

// ---------------------------------------------------------------------------
// QKV epilogue: RMS-norm(q,k) + partial RoPE + q_gain (fp32), then hi/lo bf16
// split for q,k ; v += ve_embed (plain bf16).
// qn2 [B][NH][T][256] (hi|lo), kn2 [B][NKV][T][256], vn [B][NKV][T][128].
// ---------------------------------------------------------------------------
__global__ __launch_bounds__(256) void k_qkv_epi(
    const float* __restrict__ qraw, const float* __restrict__ kvraw,
    const float* __restrict__ ve, const float* __restrict__ qgain,
    const float* __restrict__ ctab, const float* __restrict__ stab,
    bf16_t* __restrict__ qn2, bf16_t* __restrict__ kn2, bf16_t* __restrict__ vn)
{
  const int blk = blockIdx.x;           // b*2048 + t
  const int b = blk >> 11, t = blk & 2047;
  const int w = threadIdx.x >> 6, l = threadIdx.x & 63;
  const int i32 = l & 31;
  const float c = ctab[t * 32 + i32], s = stab[t * 32 + i32];
  const float EPS = 1.1920929e-07f;

  auto store_hl = [&](bf16_t* orow, int d, float v) {
    const bf16_t h = to_bf16(v);
    orow[d] = h;
    orow[128 + d] = to_bf16(v - (float)h);
  };

  // Q: wave w handles heads w, w+4, w+8, w+12
#pragma unroll
  for (int it = 0; it < 4; ++it) {
    const int h = w + it * 4;
    const float* row = qraw + (size_t)blk * 2048 + h * 128;
    float x0 = row[l], x1 = row[l + 64];
    float ss = x0 * x0 + x1 * x1;
#pragma unroll
    for (int off = 32; off; off >>= 1) ss += __shfl_xor(ss, off);
    const float rn = rsqrtf(ss * (1.0f / 128.0f) + EPS);
    x0 *= rn; x1 *= rn;
    const float p = __shfl_xor(x0, 32);
    float xr = (l < 32) ? (x0 * c - p * s) : (p * s + x0 * c);
    const float g = qgain[h];
    xr *= g; x1 *= g;
    bf16_t* orow = qn2 + (((size_t)(b * 16 + h)) * 2048 + t) * 256;
    store_hl(orow, l, xr);
    store_hl(orow, l + 64, x1);
  }
  // K: wave w -> kv head w
  {
    const float* row = kvraw + (size_t)blk * 1024 + w * 128;
    float x0 = row[l], x1 = row[l + 64];
    float ss = x0 * x0 + x1 * x1;
#pragma unroll
    for (int off = 32; off; off >>= 1) ss += __shfl_xor(ss, off);
    const float rn = rsqrtf(ss * (1.0f / 128.0f) + EPS);
    x0 *= rn; x1 *= rn;
    const float p = __shfl_xor(x0, 32);
    float xr = (l < 32) ? (x0 * c - p * s) : (p * s + x0 * c);
    bf16_t* orow = kn2 + (((size_t)(b * 4 + w)) * 2048 + t) * 256;
    store_hl(orow, l, xr);
    store_hl(orow, l + 64, x1);
  }
  // V: wave w -> kv head w ; v = vraw + ve
  {
    const float* row = kvraw + (size_t)blk * 1024 + 512 + w * 128;
    const float* verow = ve + (size_t)blk * 512 + w * 128;
    bf16_t* orow = vn + (((size_t)(b * 4 + w)) * 2048 + t) * 128;
    orow[l] = to_bf16(row[l] + verow[l]);
    orow[l + 64] = to_bf16(row[l + 64] + verow[l + 64]);
  }
}

// ---------------------------------------------------------------------------
// Causal GQA flash attention, hi/lo q,k (3-term QK^T).
// Block = (bh, qty): qt = 31 - qty (longest first).  QBLK=64: 4 waves x 16
// q-rows.  KVBLK=64.  K hi/lo in lsK[0/1] [64][136]; V^T in lsV [128][72]
// with XOR swizzle col' = kv ^ ((d>>3 & 7)<<3); P per-wave aliases lsK[0].
// ---------------------------------------------------------------------------
__global__ __launch_bounds__(256, 2) void k_attn(
    const bf16_t* __restrict__ qn2, const bf16_t* __restrict__ kn2,
    const bf16_t* __restrict__ vn, bf16_t* __restrict__ y)
{
  __shared__ __align__(16) bf16_t lsK[2][64 * 136];   // 34816 B (P scratch too)
  __shared__ __align__(16) bf16_t lsV[128 * 72];      // 18432 B
  const int qt = 31 - (int)blockIdx.y;  // longest blocks dispatched first
  const int bh = blockIdx.x;            // 0..31
  const int b = bh >> 4, h = bh & 15, kvh = h >> 2;
  const int tid = threadIdx.x, w = tid >> 6, l = tid & 63;
  const int lrow = l & 15, lk = l >> 4;
  const int q0 = qt * 64;
  const int qbase = q0 + w * 16;
  constexpr float SCALE = 0.088388347648318447f;  // 1/sqrt(128)
  constexpr float NEG = -1e30f;
  bf16_t* lsP = &lsK[0][0] + w * (16 * 72);       // per-wave P tile [16][72]

  // Q fragments (A-frag: row = lane&15, k = (lane>>4)*8+j), hi and lo
  const bf16_t* qp = qn2 + ((size_t)(b * 16 + h) * 2048) * 256;
  bf16x8 aQh[4], aQl[4];
#pragma unroll
  for (int kf = 0; kf < 4; ++kf) {
    const size_t base = (size_t)(qbase + lrow) * 256 + kf * 32 + lk * 8;
    aQh[kf] = *reinterpret_cast<const bf16x8*>(qp + base);
    aQl[kf] = *reinterpret_cast<const bf16x8*>(qp + base + 128);
  }

  const bf16_t* kp = kn2 + ((size_t)(b * 4 + kvh) * 2048) * 256;
  const bf16_t* vp = vn + ((size_t)(b * 4 + kvh) * 2048) * 128;

  f32x4 o[8] = {};
  float mstate[4], lstate[4];
#pragma unroll
  for (int rg = 0; rg < 4; ++rg) { mstate[rg] = NEG; lstate[rg] = 0.f; }

  const int ntiles = qt + 1;
  for (int tt = 0; tt < ntiles; ++tt) {
    const int t0 = tt * 64;
    __syncthreads();  // prior tile's P/V reads done before restage
    // stage K hi+lo: 64 rows x 256 cols (hi -> lsK[0], lo -> lsK[1])
#pragma unroll
    for (int it = 0; it < 8; ++it) {
      const int cch = tid + it * 256;
      const int r = cch >> 5, c5 = cch & 31;
      const bf16x8 v8 = *reinterpret_cast<const bf16x8*>(kp + (size_t)(t0 + r) * 256 + c5 * 8);
      if (c5 < 16) *reinterpret_cast<bf16x8*>(&lsK[0][r * 136 + c5 * 8]) = v8;
      else         *reinterpret_cast<bf16x8*>(&lsK[1][r * 136 + (c5 - 16) * 8]) = v8;
    }
    // stage V^T [128 d][72], col' = kv ^ ((d>>3 & 7)<<3)  (2-way writes)
#pragma unroll
    for (int it = 0; it < 4; ++it) {
      const int cch = tid + it * 256;
      const int kv = cch >> 4, dg = cch & 15;
      const bf16x8 v8 = *reinterpret_cast<const bf16x8*>(vp + (size_t)(t0 + kv) * 128 + dg * 8);
      const int colb = kv ^ ((dg & 7) << 3);
#pragma unroll
      for (int j = 0; j < 8; ++j) lsV[(dg * 8 + j) * 72 + colb] = v8[j];
    }
    __syncthreads();

    // S = Qh*Kh + Ql*Kh + Qh*Kl   (16 q-rows x 64 kv)
    f32x4 sacc[4] = {};
#pragma unroll
    for (int cf = 0; cf < 4; ++cf)
#pragma unroll
      for (int kf = 0; kf < 4; ++kf) {
        const int ofs = (cf * 16 + lrow) * 136 + kf * 32 + lk * 8;
        const bf16x8 bKh = *reinterpret_cast<const bf16x8*>(&lsK[0][ofs]);
        const bf16x8 bKl = *reinterpret_cast<const bf16x8*>(&lsK[1][ofs]);
        sacc[cf] = MFMA16(aQh[kf], bKh, sacc[cf]);
        sacc[cf] = MFMA16(aQl[kf], bKh, sacc[cf]);
        sacc[cf] = MFMA16(aQh[kf], bKl, sacc[cf]);
      }
    __syncthreads();  // all waves done reading K before P overwrites lsK[0]

    // online softmax (row: q = qbase + lk*4 + rg ; cols kv = cf*16+lrow)
    const bool domask = (tt == qt);
#pragma unroll
    for (int rg = 0; rg < 4; ++rg) {
      const int qi = qbase + lk * 4 + rg;
      float mx = NEG;
#pragma unroll
      for (int cf = 0; cf < 4; ++cf) {
        float sv = sacc[cf][rg] * SCALE;
        if (domask && (t0 + cf * 16 + lrow > qi)) sv = NEG;
        sacc[cf][rg] = sv;
        mx = fmaxf(mx, sv);
      }
      mx = fmaxf(mx, __shfl_xor(mx, 1));
      mx = fmaxf(mx, __shfl_xor(mx, 2));
      mx = fmaxf(mx, __shfl_xor(mx, 4));
      mx = fmaxf(mx, __shfl_xor(mx, 8));
      const float mold = mstate[rg];
      const float mnew = fmaxf(mold, mx);
      mstate[rg] = mnew;
      const float alpha = __expf(mold - mnew);
      float rsum = 0.f;
#pragma unroll
      for (int cf = 0; cf < 4; ++cf) {
        const float p = __expf(sacc[cf][rg] - mnew);
        sacc[cf][rg] = p;
        rsum += p;
      }
      rsum += __shfl_xor(rsum, 1);
      rsum += __shfl_xor(rsum, 2);
      rsum += __shfl_xor(rsum, 4);
      rsum += __shfl_xor(rsum, 8);
      lstate[rg] = lstate[rg] * alpha + rsum;
#pragma unroll
      for (int df = 0; df < 8; ++df) o[df][rg] *= alpha;
    }

    // P -> per-wave LDS (A-frag layout [16][72]), then PV
#pragma unroll
    for (int cf = 0; cf < 4; ++cf)
#pragma unroll
      for (int rg = 0; rg < 4; ++rg)
        lsP[(lk * 4 + rg) * 72 + cf * 16 + lrow] = to_bf16(sacc[cf][rg]);
#pragma unroll
    for (int k2 = 0; k2 < 2; ++k2) {
      const bf16x8 aP = *reinterpret_cast<const bf16x8*>(
          &lsP[lrow * 72 + k2 * 32 + lk * 8]);
#pragma unroll
      for (int df = 0; df < 8; ++df) {
        const int row = df * 16 + lrow;
        const int colb = (k2 * 32 + lk * 8) ^ (((row >> 3) & 7) << 3);
        const bf16x8 bV = *reinterpret_cast<const bf16x8*>(&lsV[row * 72 + colb]);
        o[df] = MFMA16(aP, bV, o[df]);
      }
    }
  }

  // normalize + write y [b][t][h*128+d]
#pragma unroll
  for (int rg = 0; rg < 4; ++rg) {
    const float inv = 1.0f / lstate[rg];
    const int qi = qbase + lk * 4 + rg;
    const size_t rowoff = ((size_t)(b * 2048 + qi)) * 2048 + h * 128;
#pragma unroll
    for (int df = 0; df < 8; ++df)
      y[rowoff + df * 16 + lrow] = to_bf16(o[df][rg] * inv);
  }
}

// ---------------------------------------------------------------------------
extern "C" void kernel_launch(void* const* d_in, const int* in_sizes, int n_in,
                              void* d_out, int out_size, void* d_ws, size_t ws_size,
                              hipStream_t stream) {
  const float* x  = (const float*)d_in[0];
  const float* ve = (const float*)d_in[1];
  const float* Wq = (const float*)d_in[2];
  const float* Wk = (const float*)d_in[3];
  const float* Wv = (const float*)d_in[4];
  const float* Wp = (const float*)d_in[5];
  const float* qg = (const float*)d_in[6];
  float* out = (float*)d_out;

  char* ws = (char*)d_ws;
  size_t off = 0;
  auto alloc = [&](size_t bytes) -> char* {
    char* p = ws + off;
    off += (bytes + 255) & ~(size_t)255;
    return p;
  };

  bf16_t* x3    = (bf16_t*)alloc((size_t)4096 * 6144 * 2);  // [xh|xl|xh]; later qn2
  bf16_t* wq3   = (bf16_t*)alloc((size_t)2048 * 6144 * 2);  // [Wh|Wh|Wl]
  bf16_t* wkv3  = (bf16_t*)alloc((size_t)1024 * 6144 * 2);  // rows: Wk then Wv
  bf16_t* wpb   = (bf16_t*)alloc((size_t)2048 * 2048 * 2);
  float*  qraw  = (float*)alloc((size_t)4096 * 2048 * 4);
  float*  kvraw = (float*)alloc((size_t)4096 * 1024 * 4);   // later yb
  bf16_t* kn2   = (bf16_t*)alloc((size_t)2 * 4 * 2048 * 256 * 2);
  bf16_t* vn    = (bf16_t*)alloc((size_t)2 * 4 * 2048 * 128 * 2);
  float*  ctab  = (float*)alloc((size_t)2048 * 32 * 4);
  float*  stab  = (float*)alloc((size_t)2048 * 32 * 4);
  bf16_t* qn2   = x3;              // x3 dead after GEMMs (32MB <= 50MB)
  bf16_t* yb    = (bf16_t*)kvraw;  // kvraw dead after epilogue
  (void)ws_size; (void)in_sizes; (void)n_in; (void)out_size;

  k_split_x<<<2048, 256, 0, stream>>>(x, x3);
  k_split_w<<<1024, 256, 0, stream>>>(Wq, wq3, (long)2048 * 2048);
  k_split_w<<<512,  256, 0, stream>>>(Wk, wkv3, (long)512 * 2048);
  k_split_w<<<512,  256, 0, stream>>>(Wv, wkv3 + (size_t)512 * 6144, (long)512 * 2048);
  k_cast_bf16<<<1024, 256, 0, stream>>>(Wp, wpb, (long)2048 * 2048);
  k_rope_tab<<<256, 256, 0, stream>>>(ctab, stab);

  // qraw = [xh|xl|xh]·[Wh|Wh|Wl]^T  (single pass, K=6144)
  k_gemm_bt<<<dim3(16, 32), 256, 0, stream>>>(x3, wq3, qraw, 4096, 2048, 6144, 6144, 6144);
  k_gemm_bt<<<dim3(8, 32),  256, 0, stream>>>(x3, wkv3, kvraw, 4096, 1024, 6144, 6144, 6144);

  k_qkv_epi<<<4096, 256, 0, stream>>>(qraw, kvraw, ve, qg, ctab, stab, qn2, kn2, vn);

  k_attn<<<dim3(32, 32), 256, 0, stream>>>(qn2, kn2, vn, yb);

  k_gemm_bt<<<dim3(16, 32), 256, 0, stream>>>(yb, wpb, out, 4096, 2048, 2048, 2048, 2048);
}